// Round 1
// baseline (627.487 us; speedup 1.0000x reference)
//
#include <hip/hip_runtime.h>

typedef unsigned short u16;
typedef __attribute__((ext_vector_type(8))) short short8;
typedef __attribute__((ext_vector_type(4))) float f32x4;

#define MFMA16(a, b, c) __builtin_amdgcn_mfma_f32_16x16x32_bf16((a), (b), (c), 0, 0, 0)

constexpr int Bb = 2, Ss = 4096, Tt = 4096, Dd = 512;
constexpr int BM = 32, BN = 64, TP = 4;
constexpr int TPART = Tt / TP;   // 1024
constexpr int TCH = TPART / BN;  // 16 T-chunks per partition

// ---- workspace layout (bytes) ----
constexpr size_t SZ_BF = (size_t)Bb * Tt * Dd * 2;  // 8,388,608 B: one bf16 [2][4096][512]
constexpr size_t O_D2TH = 0;
constexpr size_t O_D2TL = O_D2TH + SZ_BF;
constexpr size_t O_D3T  = O_D2TL + SZ_BF;
constexpr size_t O_D4T  = O_D3T + SZ_BF;
constexpr size_t O_CTX  = O_D4T + (size_t)512 * 512 * 2;
constexpr size_t O_OP   = O_CTX + SZ_BF;
constexpr size_t O_MP   = O_OP + (size_t)TP * SZ_BF;
constexpr size_t O_LP   = O_MP + (size_t)TP * Bb * Ss * 4;

__device__ __forceinline__ u16 f2bf(float x) {
  union { float f; unsigned u; } v; v.f = x;
  unsigned r = v.u + 0x7fffu + ((v.u >> 16) & 1u);  // RNE
  return (u16)(r >> 16);
}
__device__ __forceinline__ float bf2f(u16 h) {
  union { unsigned u; float f; } v; v.u = ((unsigned)h) << 16;
  return v.f;
}

// in: [batch][R][C] f32  ->  outh/outl: [batch][C][R] bf16 (hi, optional lo residual)
__global__ void transpose_split_kernel(const float* __restrict__ in,
                                       u16* __restrict__ outh,
                                       u16* __restrict__ outl,
                                       int R, int C) {
  __shared__ float tile[32][33];
  int b = blockIdx.z;
  const float* inb = in + (size_t)b * R * C;
  int x = blockIdx.x * 32 + threadIdx.x;
  int y0 = blockIdx.y * 32;
  for (int j = threadIdx.y; j < 32; j += 8)
    tile[j][threadIdx.x] = inb[(size_t)(y0 + j) * C + x];
  __syncthreads();
  size_t ob = (size_t)b * C * R;
  for (int j = threadIdx.y; j < 32; j += 8) {
    float v = tile[threadIdx.x][j];
    size_t oi = ob + (size_t)(blockIdx.x * 32 + j) * R + (y0 + threadIdx.x);
    u16 h = f2bf(v);
    outh[oi] = h;
    if (outl) outl[oi] = f2bf(v - bf2f(h));
  }
}

// Flash attention partial over one T-partition.
// grid (Ss/BM, TP, Bb), block 128 (2 waves; wave w owns rows w*16..w*16+15)
__global__ __launch_bounds__(128, 2)
void flash_part_kernel(const float* __restrict__ d1,
                       const u16* __restrict__ d2th,
                       const u16* __restrict__ d2tl,
                       const u16* __restrict__ d3t,
                       u16* __restrict__ opart,
                       float* __restrict__ mpart,
                       float* __restrict__ lpart) {
  // LDS: pitch 72 (pad +8 bf16 -> 2-way bank aliasing, free)
  __shared__ u16 qh[32 * 72], ql[32 * 72];
  __shared__ u16 kh[64 * 72], kl[64 * 72];  // kh doubles as V buffer in PV phase
  __shared__ u16 ph[32 * 72];

  const int tid = threadIdx.x;
  const int wave = tid >> 6, lane = tid & 63, quad = lane >> 4, l15 = lane & 15;
  const int m0 = wave * 16;
  const int sblk = blockIdx.x, tp = blockIdx.y, b = blockIdx.z;
  const int s0 = sblk * BM;

  f32x4 o_acc[32];
#pragma unroll
  for (int i = 0; i < 32; i++) o_acc[i] = (f32x4){0.f, 0.f, 0.f, 0.f};
  float m_r[4] = {-INFINITY, -INFINITY, -INFINITY, -INFINITY};
  float l_r[4] = {0.f, 0.f, 0.f, 0.f};

  const float* q_base = d1 + ((size_t)b * Ss + s0) * Dd;
  const u16* kh_base = d2th + (size_t)b * Tt * Dd;
  const u16* kl_base = d2tl + (size_t)b * Tt * Dd;
  const u16* v_base  = d3t  + (size_t)b * Dd * Tt;

  // staging index precompute
  const int qrow = tid >> 2, qcol = (tid & 3) * 16;  // 32 rows x 64 cols f32
  const int krow = tid >> 1, kcol = (tid & 1) * 32;  // 64 rows x 64 cols bf16

  for (int tc = 0; tc < TCH; tc++) {
    const int t0 = tp * TPART + tc * BN;
    f32x4 s_acc[4];
#pragma unroll
    for (int nt = 0; nt < 4; nt++) s_acc[nt] = (f32x4){0.f, 0.f, 0.f, 0.f};

    // ---- QK^T over D in chunks of 64 ----
    for (int ds = 0; ds < 8; ds++) {
      const int d0 = ds * 64;
      __syncthreads();
      {  // stage Q chunk (f32 -> hi/lo bf16)
        const float* src = q_base + (size_t)qrow * Dd + d0 + qcol;
        u16* dh = &qh[qrow * 72 + qcol];
        u16* dl = &ql[qrow * 72 + qcol];
#pragma unroll
        for (int u = 0; u < 16; u += 4) {
          float4 v = *(const float4*)(src + u);
          ushort4 hh, ll;
          hh.x = f2bf(v.x); ll.x = f2bf(v.x - bf2f(hh.x));
          hh.y = f2bf(v.y); ll.y = f2bf(v.y - bf2f(hh.y));
          hh.z = f2bf(v.z); ll.z = f2bf(v.z - bf2f(hh.z));
          hh.w = f2bf(v.w); ll.w = f2bf(v.w - bf2f(hh.w));
          *(ushort4*)(dh + u) = hh;
          *(ushort4*)(dl + u) = ll;
        }
      }
      {  // stage K chunk (pre-converted bf16 hi/lo, [t][d] layout)
        const u16* sh = kh_base + (size_t)(t0 + krow) * Dd + d0 + kcol;
        const u16* sl = kl_base + (size_t)(t0 + krow) * Dd + d0 + kcol;
        u16* dh = &kh[krow * 72 + kcol];
        u16* dl = &kl[krow * 72 + kcol];
#pragma unroll
        for (int u = 0; u < 32; u += 8) {
          *(uint4*)(dh + u) = *(const uint4*)(sh + u);
          *(uint4*)(dl + u) = *(const uint4*)(sl + u);
        }
      }
      __syncthreads();
#pragma unroll
      for (int ks = 0; ks < 2; ks++) {
        const int kk = ks * 32 + quad * 8;
        short8 ah = *(const short8*)&qh[(m0 + l15) * 72 + kk];
        short8 al = *(const short8*)&ql[(m0 + l15) * 72 + kk];
#pragma unroll
        for (int nt = 0; nt < 4; nt++) {
          short8 bh = *(const short8*)&kh[(nt * 16 + l15) * 72 + kk];
          short8 bl = *(const short8*)&kl[(nt * 16 + l15) * 72 + kk];
          s_acc[nt] = MFMA16(ah, bh, s_acc[nt]);
          s_acc[nt] = MFMA16(al, bh, s_acc[nt]);
          s_acc[nt] = MFMA16(ah, bl, s_acc[nt]);
        }
      }
    }

    // ---- online softmax (rows fully intra-wave; C layout: row=quad*4+r, col=nt*16+l15) ----
    float alpha[4], psum[4];
#pragma unroll
    for (int r = 0; r < 4; r++) {
      float v = fmaxf(fmaxf(s_acc[0][r], s_acc[1][r]), fmaxf(s_acc[2][r], s_acc[3][r]));
      v = fmaxf(v, __shfl_xor(v, 1));
      v = fmaxf(v, __shfl_xor(v, 2));
      v = fmaxf(v, __shfl_xor(v, 4));
      v = fmaxf(v, __shfl_xor(v, 8));
      float mn = fmaxf(m_r[r], v);
      alpha[r] = __expf(m_r[r] - mn);
      m_r[r] = mn;
      psum[r] = 0.f;
    }
#pragma unroll
    for (int nt = 0; nt < 4; nt++) {
#pragma unroll
      for (int r = 0; r < 4; r++) {
        float p = __expf(s_acc[nt][r] - m_r[r]);
        psum[r] += p;
        ph[(m0 + quad * 4 + r) * 72 + nt * 16 + l15] = f2bf(p);
      }
    }
#pragma unroll
    for (int r = 0; r < 4; r++) {
      float v = psum[r];
      v += __shfl_xor(v, 1);
      v += __shfl_xor(v, 2);
      v += __shfl_xor(v, 4);
      v += __shfl_xor(v, 8);
      l_r[r] = l_r[r] * alpha[r] + v;
    }
#pragma unroll
    for (int j = 0; j < 32; j++) {
#pragma unroll
      for (int r = 0; r < 4; r++) o_acc[j][r] *= alpha[r];
    }

    // ---- PV: O += P @ V, output cols in chunks of 64 ----
#pragma unroll
    for (int nc = 0; nc < 8; nc++) {
      __syncthreads();
      {  // stage V chunk [64 d][64 t] into kh buffer (d3t is [b][d][t])
        const u16* sv = v_base + (size_t)(nc * 64 + krow) * Tt + t0 + kcol;
        u16* dv = &kh[krow * 72 + kcol];
#pragma unroll
        for (int u = 0; u < 32; u += 8) *(uint4*)(dv + u) = *(const uint4*)(sv + u);
      }
      __syncthreads();
#pragma unroll
      for (int ks = 0; ks < 2; ks++) {
        const int kk = ks * 32 + quad * 8;
        short8 ap = *(const short8*)&ph[(m0 + l15) * 72 + kk];
#pragma unroll
        for (int nt = 0; nt < 4; nt++) {
          short8 bv = *(const short8*)&kh[(nt * 16 + l15) * 72 + kk];
          o_acc[nc * 4 + nt] = MFMA16(ap, bv, o_acc[nc * 4 + nt]);
        }
      }
    }
  }

  // ---- epilogue: unnormalized partial O (bf16) + m/l stats ----
  const size_t obase = (((size_t)tp * Bb + b) * Ss + s0) * Dd;
#pragma unroll
  for (int j = 0; j < 32; j++) {
    const int col = (j >> 2) * 64 + (j & 3) * 16 + l15;
#pragma unroll
    for (int r = 0; r < 4; r++) {
      const int row = m0 + quad * 4 + r;
      opart[obase + (size_t)row * Dd + col] = f2bf(o_acc[j][r]);
    }
  }
  if (l15 == 0) {
    const size_t sbase = ((size_t)tp * Bb + b) * Ss + s0;
#pragma unroll
    for (int r = 0; r < 4; r++) {
      const int row = m0 + quad * 4 + r;
      mpart[sbase + row] = m_r[r];
      lpart[sbase + row] = l_r[r];
    }
  }
}

// Merge TP partitions: ctx = sum_p e^{m_p-M} O_p / sum_p e^{m_p-M} l_p
__global__ void combine_kernel(const u16* __restrict__ opart,
                               const float* __restrict__ mpart,
                               const float* __restrict__ lpart,
                               u16* __restrict__ ctx) {
  const int idx = blockIdx.x * blockDim.x + threadIdx.x;  // vec8 index
  const int vpr = Dd / 8;
  const int row = idx / vpr;         // b*Ss + s
  const int dv = (idx % vpr) * 8;
  float mv[TP], mM = -INFINITY;
#pragma unroll
  for (int p = 0; p < TP; p++) {
    mv[p] = mpart[(size_t)p * Bb * Ss + row];
    mM = fmaxf(mM, mv[p]);
  }
  float w[TP], denom = 0.f;
#pragma unroll
  for (int p = 0; p < TP; p++) {
    float e = __expf(mv[p] - mM);
    w[p] = e;
    denom += e * lpart[(size_t)p * Bb * Ss + row];
  }
  const float inv = 1.0f / denom;
  float acc[8];
#pragma unroll
  for (int e = 0; e < 8; e++) acc[e] = 0.f;
#pragma unroll
  for (int p = 0; p < TP; p++) {
    uint4 raw = *(const uint4*)&opart[(size_t)p * Bb * Ss * Dd + (size_t)row * Dd + dv];
    const u16* u = (const u16*)&raw;
#pragma unroll
    for (int e = 0; e < 8; e++) acc[e] += w[p] * bf2f(u[e]);
  }
  u16 outv[8];
#pragma unroll
  for (int e = 0; e < 8; e++) outv[e] = f2bf(acc[e] * inv);
  *(uint4*)&ctx[(size_t)row * Dd + dv] = *(const uint4*)outv;
}

// out[8192,512] = ctx_bf16 @ d4 + d5 ; 128x128 tile, 256 thr, wave = 64x64
__global__ __launch_bounds__(256, 2)
void proj_kernel(const u16* __restrict__ ctx,
                 const u16* __restrict__ d4t,  // [n][k]
                 const float* __restrict__ d5,
                 float* __restrict__ out) {
  __shared__ u16 a_lds[128 * 40], b_lds[128 * 40];
  const int tid = threadIdx.x;
  const int wave = tid >> 6, lane = tid & 63, quad = lane >> 4, l15 = lane & 15;
  const int m0w = (wave & 1) * 64, n0w = (wave >> 1) * 64;
  const int bm = blockIdx.x, bn = blockIdx.y;
  f32x4 acc[4][4];
#pragma unroll
  for (int i = 0; i < 4; i++)
#pragma unroll
    for (int j = 0; j < 4; j++) acc[i][j] = (f32x4){0.f, 0.f, 0.f, 0.f};

  const int srow = tid >> 2, scol = (tid & 3) * 8;
  for (int kt = 0; kt < 16; kt++) {
    const int k0 = kt * 32;
    __syncthreads();
#pragma unroll
    for (int pass = 0; pass < 2; pass++) {
      const int row = srow + pass * 64;
      *(uint4*)&a_lds[row * 40 + scol] =
          *(const uint4*)&ctx[(size_t)(bm * 128 + row) * Dd + k0 + scol];
      *(uint4*)&b_lds[row * 40 + scol] =
          *(const uint4*)&d4t[(size_t)(bn * 128 + row) * Dd + k0 + scol];
    }
    __syncthreads();
    short8 af[4], bfr[4];
#pragma unroll
    for (int i = 0; i < 4; i++)
      af[i] = *(const short8*)&a_lds[(m0w + 16 * i + l15) * 40 + quad * 8];
#pragma unroll
    for (int j = 0; j < 4; j++)
      bfr[j] = *(const short8*)&b_lds[(n0w + 16 * j + l15) * 40 + quad * 8];
#pragma unroll
    for (int i = 0; i < 4; i++)
#pragma unroll
      for (int j = 0; j < 4; j++) acc[i][j] = MFMA16(af[i], bfr[j], acc[i][j]);
  }
#pragma unroll
  for (int j = 0; j < 4; j++) {
    const int colg = bn * 128 + n0w + 16 * j + l15;
    const float bias = d5[colg];
#pragma unroll
    for (int i = 0; i < 4; i++) {
#pragma unroll
      for (int r = 0; r < 4; r++) {
        const int rowg = bm * 128 + m0w + 16 * i + quad * 4 + r;
        out[(size_t)rowg * 512 + colg] = acc[i][j][r] + bias;
      }
    }
  }
}

extern "C" void kernel_launch(void* const* d_in, const int* in_sizes, int n_in,
                              void* d_out, int out_size, void* d_ws, size_t ws_size,
                              hipStream_t stream) {
  (void)in_sizes; (void)n_in; (void)out_size; (void)ws_size;
  const float* d1 = (const float*)d_in[0];
  const float* d2 = (const float*)d_in[1];
  const float* d3 = (const float*)d_in[2];
  const float* d4 = (const float*)d_in[3];
  const float* d5 = (const float*)d_in[4];
  float* out = (float*)d_out;
  char* ws = (char*)d_ws;

  u16* d2th = (u16*)(ws + O_D2TH);
  u16* d2tl = (u16*)(ws + O_D2TL);
  u16* d3t  = (u16*)(ws + O_D3T);
  u16* d4t  = (u16*)(ws + O_D4T);
  u16* ctx  = (u16*)(ws + O_CTX);
  u16* opart = (u16*)(ws + O_OP);
  float* mpart = (float*)(ws + O_MP);
  float* lpart = (float*)(ws + O_LP);

  // d2 [b][512][4096] -> [b][t][d] hi+lo
  transpose_split_kernel<<<dim3(128, 16, 2), dim3(32, 8), 0, stream>>>(d2, d2th, d2tl, 512, 4096);
  // d3 [b][4096][512] -> [b][d][t] hi only
  transpose_split_kernel<<<dim3(16, 128, 2), dim3(32, 8), 0, stream>>>(d3, d3t, nullptr, 4096, 512);
  // d4 [512][512] -> [n][k] hi only
  transpose_split_kernel<<<dim3(16, 16, 1), dim3(32, 8), 0, stream>>>(d4, d4t, nullptr, 512, 512);

  flash_part_kernel<<<dim3(Ss / BM, TP, Bb), 128, 0, stream>>>(d1, d2th, d2tl, d3t,
                                                               opart, mpart, lpart);
  combine_kernel<<<(Bb * Ss * Dd / 8) / 256, 256, 0, stream>>>(opart, mpart, lpart, ctx);
  proj_kernel<<<dim3(64, 4), 256, 0, stream>>>(ctx, d4t, d5, out);
}

// Round 2
// 516.429 us; speedup vs baseline: 1.2151x; 1.2151x over previous
//
#include <hip/hip_runtime.h>

typedef unsigned short u16;
typedef __attribute__((ext_vector_type(8))) short short8;
typedef __attribute__((ext_vector_type(4))) float f32x4;

#define MFMA16(a, b, c) __builtin_amdgcn_mfma_f32_16x16x32_bf16((a), (b), (c), 0, 0, 0)

constexpr int Bb = 2, Ss = 4096, Tt = 4096, Dd = 512;
constexpr int BM = 64, BN = 64, TP = 4;
constexpr int TPART = Tt / TP;   // 1024
constexpr int TCH = TPART / BN;  // 16 T-chunks per partition

// ---- workspace layout (bytes) ----
constexpr size_t SZ_BF = (size_t)Bb * Ss * Dd * 2;  // 8,388,608 B: one bf16 [2][4096][512]
constexpr size_t O_QH  = 0;
constexpr size_t O_QL  = O_QH + SZ_BF;
constexpr size_t O_D2TH = O_QL + SZ_BF;
constexpr size_t O_D2TL = O_D2TH + SZ_BF;
constexpr size_t O_D3T  = O_D2TL + SZ_BF;
constexpr size_t O_D4T  = O_D3T + SZ_BF;
constexpr size_t O_CTX  = O_D4T + (size_t)512 * 512 * 2;
constexpr size_t O_OP   = O_CTX + SZ_BF;
constexpr size_t O_MP   = O_OP + (size_t)TP * SZ_BF;
constexpr size_t O_LP   = O_MP + (size_t)TP * Bb * Ss * 4;

__device__ __forceinline__ u16 f2bf(float x) {
  union { float f; unsigned u; } v; v.f = x;
  unsigned r = v.u + 0x7fffu + ((v.u >> 16) & 1u);  // RNE
  return (u16)(r >> 16);
}
__device__ __forceinline__ float bf2f(u16 h) {
  union { unsigned u; float f; } v; v.u = ((unsigned)h) << 16;
  return v.f;
}

// elementwise f32 -> bf16 hi + bf16 lo-residual (no transpose; d1 is already [b][s][d])
__global__ void cvt_split_kernel(const float* __restrict__ in,
                                 u16* __restrict__ outh, u16* __restrict__ outl) {
  const int i = blockIdx.x * 256 + threadIdx.x;
  float4 v = ((const float4*)in)[i];
  ushort4 hh, ll;
  hh.x = f2bf(v.x); ll.x = f2bf(v.x - bf2f(hh.x));
  hh.y = f2bf(v.y); ll.y = f2bf(v.y - bf2f(hh.y));
  hh.z = f2bf(v.z); ll.z = f2bf(v.z - bf2f(hh.z));
  hh.w = f2bf(v.w); ll.w = f2bf(v.w - bf2f(hh.w));
  ((ushort4*)outh)[i] = hh;
  ((ushort4*)outl)[i] = ll;
}

// in: [batch][R][C] f32  ->  outh/outl: [batch][C][R] bf16 (hi, optional lo residual)
__global__ void transpose_split_kernel(const float* __restrict__ in,
                                       u16* __restrict__ outh,
                                       u16* __restrict__ outl,
                                       int R, int C) {
  __shared__ float tile[32][33];
  int b = blockIdx.z;
  const float* inb = in + (size_t)b * R * C;
  int x = blockIdx.x * 32 + threadIdx.x;
  int y0 = blockIdx.y * 32;
  for (int j = threadIdx.y; j < 32; j += 8)
    tile[j][threadIdx.x] = inb[(size_t)(y0 + j) * C + x];
  __syncthreads();
  size_t ob = (size_t)b * C * R;
  for (int j = threadIdx.y; j < 32; j += 8) {
    float v = tile[threadIdx.x][j];
    size_t oi = ob + (size_t)(blockIdx.x * 32 + j) * R + (y0 + threadIdx.x);
    u16 h = f2bf(v);
    outh[oi] = h;
    if (outl) outl[oi] = f2bf(v - bf2f(h));
  }
}

// Flash attention partial over one T-partition.
// grid (Ss/BM=64, TP, Bb), block 256 (4 waves; wave w owns Q-rows w*16..w*16+15)
__global__ __launch_bounds__(256, 2)
void flash_part_kernel(const u16* __restrict__ qh_g,
                       const u16* __restrict__ ql_g,
                       const u16* __restrict__ d2th,
                       const u16* __restrict__ d2tl,
                       const u16* __restrict__ d3t,
                       u16* __restrict__ opart,
                       float* __restrict__ mpart,
                       float* __restrict__ lpart) {
  // K tile: 64 t-rows x 128 d-cols, pitch 136 (pad+8 -> 2-way bank alias, free; 16B-aligned rows)
  // V tile: 128 d-rows x 64 t-cols, pitch 72
  // P tile: 64 s-rows x 64 t-cols, pitch 72 (per-wave private rows; no cross-wave hazard)
  __shared__ u16 kh[64 * 136], kl[64 * 136];
  __shared__ u16 vb[128 * 72];
  __shared__ u16 ph[64 * 72];

  const int tid = threadIdx.x;
  const int wave = tid >> 6, lane = tid & 63, quad = lane >> 4, l15 = lane & 15;
  const int m0 = wave * 16;
  const int s0 = blockIdx.x * BM, tp = blockIdx.y, b = blockIdx.z;

  f32x4 o_acc[32];
#pragma unroll
  for (int i = 0; i < 32; i++) o_acc[i] = (f32x4){0.f, 0.f, 0.f, 0.f};
  float m_r[4] = {-INFINITY, -INFINITY, -INFINITY, -INFINITY};
  float l_r[4] = {0.f, 0.f, 0.f, 0.f};

  const u16* qh_row = qh_g + ((size_t)b * Ss + s0 + m0 + l15) * Dd + quad * 8;
  const u16* ql_row = ql_g + ((size_t)b * Ss + s0 + m0 + l15) * Dd + quad * 8;
  const u16* kh_b = d2th + (size_t)b * Tt * Dd;
  const u16* kl_b = d2tl + (size_t)b * Tt * Dd;
  const u16* v_b  = d3t  + (size_t)b * Dd * Tt;

  const int krow = tid >> 2, kcol = (tid & 3) * 32;  // K stage: 64 x 128
  const int vrow = tid >> 1, vcol = (tid & 1) * 32;  // V stage: 128 x 64

  for (int tc = 0; tc < TCH; tc++) {
    const int t0 = tp * TPART + tc * BN;
    f32x4 s_acc[4];
#pragma unroll
    for (int nt = 0; nt < 4; nt++) s_acc[nt] = (f32x4){0.f, 0.f, 0.f, 0.f};

    // ---- QK^T over D in chunks of 128 ----
    for (int ds = 0; ds < 4; ds++) {
      const int d0 = ds * 128;
      __syncthreads();
      {  // stage K chunk hi+lo (pure copies; pre-converted bf16 [t][d])
        const u16* sh = kh_b + (size_t)(t0 + krow) * Dd + d0 + kcol;
        const u16* sl = kl_b + (size_t)(t0 + krow) * Dd + d0 + kcol;
        u16* dh = &kh[krow * 136 + kcol];
        u16* dl = &kl[krow * 136 + kcol];
#pragma unroll
        for (int u = 0; u < 32; u += 8) {
          *(uint4*)(dh + u) = *(const uint4*)(sh + u);
          *(uint4*)(dl + u) = *(const uint4*)(sl + u);
        }
      }
      __syncthreads();
      // Q fragments straight from global (L2-resident, loaded once per ds)
      short8 ah[4], al[4];
#pragma unroll
      for (int ks = 0; ks < 4; ks++) {
        ah[ks] = *(const short8*)(qh_row + d0 + ks * 32);
        al[ks] = *(const short8*)(ql_row + d0 + ks * 32);
      }
#pragma unroll
      for (int ks = 0; ks < 4; ks++) {
        const int kk = ks * 32 + quad * 8;
#pragma unroll
        for (int nt = 0; nt < 4; nt++) {
          short8 bh = *(const short8*)&kh[(nt * 16 + l15) * 136 + kk];
          short8 bl = *(const short8*)&kl[(nt * 16 + l15) * 136 + kk];
          s_acc[nt] = MFMA16(ah[ks], bh, s_acc[nt]);
          s_acc[nt] = MFMA16(al[ks], bh, s_acc[nt]);
          s_acc[nt] = MFMA16(ah[ks], bl, s_acc[nt]);
        }
      }
    }

    // ---- online softmax (C layout: row=quad*4+r, col=nt*16+l15; rows intra-wave) ----
    float alpha[4], psum[4];
#pragma unroll
    for (int r = 0; r < 4; r++) {
      float v = fmaxf(fmaxf(s_acc[0][r], s_acc[1][r]), fmaxf(s_acc[2][r], s_acc[3][r]));
      v = fmaxf(v, __shfl_xor(v, 1));
      v = fmaxf(v, __shfl_xor(v, 2));
      v = fmaxf(v, __shfl_xor(v, 4));
      v = fmaxf(v, __shfl_xor(v, 8));
      float mn = fmaxf(m_r[r], v);
      alpha[r] = __expf(m_r[r] - mn);
      m_r[r] = mn;
      psum[r] = 0.f;
    }
#pragma unroll
    for (int nt = 0; nt < 4; nt++) {
#pragma unroll
      for (int r = 0; r < 4; r++) {
        float p = __expf(s_acc[nt][r] - m_r[r]);
        psum[r] += p;
        ph[(m0 + quad * 4 + r) * 72 + nt * 16 + l15] = f2bf(p);
      }
    }
#pragma unroll
    for (int r = 0; r < 4; r++) {
      float v = psum[r];
      v += __shfl_xor(v, 1);
      v += __shfl_xor(v, 2);
      v += __shfl_xor(v, 4);
      v += __shfl_xor(v, 8);
      l_r[r] = l_r[r] * alpha[r] + v;
    }
#pragma unroll
    for (int j = 0; j < 32; j++) {
#pragma unroll
      for (int r = 0; r < 4; r++) o_acc[j][r] *= alpha[r];
    }

    // ---- PV: O += P @ V, output d-cols in chunks of 128 ----
#pragma unroll
    for (int nc = 0; nc < 4; nc++) {
      __syncthreads();
      {  // stage V chunk [128 d][64 t] (d3t is [b][d][t])
        const u16* sv = v_b + (size_t)(nc * 128 + vrow) * Tt + t0 + vcol;
        u16* dv = &vb[vrow * 72 + vcol];
#pragma unroll
        for (int u = 0; u < 32; u += 8) *(uint4*)(dv + u) = *(const uint4*)(sv + u);
      }
      __syncthreads();
#pragma unroll
      for (int ks = 0; ks < 2; ks++) {
        const int kk = ks * 32 + quad * 8;
        short8 ap = *(const short8*)&ph[(m0 + l15) * 72 + kk];
#pragma unroll
        for (int nt = 0; nt < 8; nt++) {
          short8 bv = *(const short8*)&vb[(nt * 16 + l15) * 72 + kk];
          o_acc[nc * 8 + nt] = MFMA16(ap, bv, o_acc[nc * 8 + nt]);
        }
      }
    }
  }

  // ---- epilogue: unnormalized partial O (bf16) + m/l stats ----
  const size_t obase = (((size_t)tp * Bb + b) * Ss + s0) * Dd;
#pragma unroll
  for (int j = 0; j < 32; j++) {
    const int col = (j >> 3) * 128 + (j & 7) * 16 + l15;
#pragma unroll
    for (int r = 0; r < 4; r++) {
      const int row = m0 + quad * 4 + r;
      opart[obase + (size_t)row * Dd + col] = f2bf(o_acc[j][r]);
    }
  }
  if (l15 == 0) {
    const size_t sbase = ((size_t)tp * Bb + b) * Ss + s0;
#pragma unroll
    for (int r = 0; r < 4; r++) {
      const int row = m0 + quad * 4 + r;
      mpart[sbase + row] = m_r[r];
      lpart[sbase + row] = l_r[r];
    }
  }
}

// Merge TP partitions: ctx = sum_p e^{m_p-M} O_p / sum_p e^{m_p-M} l_p
__global__ void combine_kernel(const u16* __restrict__ opart,
                               const float* __restrict__ mpart,
                               const float* __restrict__ lpart,
                               u16* __restrict__ ctx) {
  const int idx = blockIdx.x * blockDim.x + threadIdx.x;  // vec8 index
  const int vpr = Dd / 8;
  const int row = idx / vpr;         // b*Ss + s
  const int dv = (idx % vpr) * 8;
  float mv[TP], mM = -INFINITY;
#pragma unroll
  for (int p = 0; p < TP; p++) {
    mv[p] = mpart[(size_t)p * Bb * Ss + row];
    mM = fmaxf(mM, mv[p]);
  }
  float w[TP], denom = 0.f;
#pragma unroll
  for (int p = 0; p < TP; p++) {
    float e = __expf(mv[p] - mM);
    w[p] = e;
    denom += e * lpart[(size_t)p * Bb * Ss + row];
  }
  const float inv = 1.0f / denom;
  float acc[8];
#pragma unroll
  for (int e = 0; e < 8; e++) acc[e] = 0.f;
#pragma unroll
  for (int p = 0; p < TP; p++) {
    uint4 raw = *(const uint4*)&opart[(size_t)p * Bb * Ss * Dd + (size_t)row * Dd + dv];
    const u16* u = (const u16*)&raw;
#pragma unroll
    for (int e = 0; e < 8; e++) acc[e] += w[p] * bf2f(u[e]);
  }
  u16 outv[8];
#pragma unroll
  for (int e = 0; e < 8; e++) outv[e] = f2bf(acc[e] * inv);
  *(uint4*)&ctx[(size_t)row * Dd + dv] = *(const uint4*)outv;
}

// out[8192,512] = ctx_bf16 @ d4 + d5 ; 128x128 tile, 256 thr, wave = 64x64
__global__ __launch_bounds__(256, 2)
void proj_kernel(const u16* __restrict__ ctx,
                 const u16* __restrict__ d4t,  // [n][k]
                 const float* __restrict__ d5,
                 float* __restrict__ out) {
  __shared__ u16 a_lds[128 * 40], b_lds[128 * 40];
  const int tid = threadIdx.x;
  const int wave = tid >> 6, lane = tid & 63, quad = lane >> 4, l15 = lane & 15;
  const int m0w = (wave & 1) * 64, n0w = (wave >> 1) * 64;
  const int bm = blockIdx.x, bn = blockIdx.y;
  f32x4 acc[4][4];
#pragma unroll
  for (int i = 0; i < 4; i++)
#pragma unroll
    for (int j = 0; j < 4; j++) acc[i][j] = (f32x4){0.f, 0.f, 0.f, 0.f};

  const int srow = tid >> 2, scol = (tid & 3) * 8;
  for (int kt = 0; kt < 16; kt++) {
    const int k0 = kt * 32;
    __syncthreads();
#pragma unroll
    for (int pass = 0; pass < 2; pass++) {
      const int row = srow + pass * 64;
      *(uint4*)&a_lds[row * 40 + scol] =
          *(const uint4*)&ctx[(size_t)(bm * 128 + row) * Dd + k0 + scol];
      *(uint4*)&b_lds[row * 40 + scol] =
          *(const uint4*)&d4t[(size_t)(bn * 128 + row) * Dd + k0 + scol];
    }
    __syncthreads();
    short8 af[4], bfr[4];
#pragma unroll
    for (int i = 0; i < 4; i++)
      af[i] = *(const short8*)&a_lds[(m0w + 16 * i + l15) * 40 + quad * 8];
#pragma unroll
    for (int j = 0; j < 4; j++)
      bfr[j] = *(const short8*)&b_lds[(n0w + 16 * j + l15) * 40 + quad * 8];
#pragma unroll
    for (int i = 0; i < 4; i++)
#pragma unroll
      for (int j = 0; j < 4; j++) acc[i][j] = MFMA16(af[i], bfr[j], acc[i][j]);
  }
#pragma unroll
  for (int j = 0; j < 4; j++) {
    const int colg = bn * 128 + n0w + 16 * j + l15;
    const float bias = d5[colg];
#pragma unroll
    for (int i = 0; i < 4; i++) {
#pragma unroll
      for (int r = 0; r < 4; r++) {
        const int rowg = bm * 128 + m0w + 16 * i + quad * 4 + r;
        out[(size_t)rowg * 512 + colg] = acc[i][j][r] + bias;
      }
    }
  }
}

extern "C" void kernel_launch(void* const* d_in, const int* in_sizes, int n_in,
                              void* d_out, int out_size, void* d_ws, size_t ws_size,
                              hipStream_t stream) {
  (void)in_sizes; (void)n_in; (void)out_size; (void)ws_size;
  const float* d1 = (const float*)d_in[0];
  const float* d2 = (const float*)d_in[1];
  const float* d3 = (const float*)d_in[2];
  const float* d4 = (const float*)d_in[3];
  const float* d5 = (const float*)d_in[4];
  float* out = (float*)d_out;
  char* ws = (char*)d_ws;

  u16* qh_g = (u16*)(ws + O_QH);
  u16* ql_g = (u16*)(ws + O_QL);
  u16* d2th = (u16*)(ws + O_D2TH);
  u16* d2tl = (u16*)(ws + O_D2TL);
  u16* d3t  = (u16*)(ws + O_D3T);
  u16* d4t  = (u16*)(ws + O_D4T);
  u16* ctx  = (u16*)(ws + O_CTX);
  u16* opart = (u16*)(ws + O_OP);
  float* mpart = (float*)(ws + O_MP);
  float* lpart = (float*)(ws + O_LP);

  // d1 [b][s][d] -> bf16 hi/lo (elementwise)
  cvt_split_kernel<<<(Bb * Ss * Dd / 4) / 256, 256, 0, stream>>>(d1, qh_g, ql_g);
  // d2 [b][512][4096] -> [b][t][d] hi+lo
  transpose_split_kernel<<<dim3(128, 16, 2), dim3(32, 8), 0, stream>>>(d2, d2th, d2tl, 512, 4096);
  // d3 [b][4096][512] -> [b][d][t] hi only
  transpose_split_kernel<<<dim3(16, 128, 2), dim3(32, 8), 0, stream>>>(d3, d3t, nullptr, 4096, 512);
  // d4 [512][512] -> [n][k] hi only
  transpose_split_kernel<<<dim3(16, 16, 1), dim3(32, 8), 0, stream>>>(d4, d4t, nullptr, 512, 512);

  flash_part_kernel<<<dim3(Ss / BM, TP, Bb), 256, 0, stream>>>(qh_g, ql_g, d2th, d2tl, d3t,
                                                               opart, mpart, lpart);
  combine_kernel<<<(Bb * Ss * Dd / 8) / 256, 256, 0, stream>>>(opart, mpart, lpart, ctx);
  proj_kernel<<<dim3(64, 4), 256, 0, stream>>>(ctx, d4t, d5, out);
}